// Round 15
// baseline (70.455 us; speedup 1.0000x reference)
//
#include <hip/hip_runtime.h>
#include <cstdint>
#include <cstddef>

#define HF 128   // hidden feature dim
#define NTY 8    // edge types

typedef __attribute__((ext_vector_type(8))) short short8;     // 8 x 16b
typedef __attribute__((ext_vector_type(8))) _Float16 half8;   // 8 fp16
typedef __attribute__((ext_vector_type(4))) float f32x4;
typedef unsigned int u32;
typedef unsigned short u16;

__device__ __forceinline__ u16 f2h(float x) {      // RNE float->fp16 bits
  union { _Float16 h; u16 u; } v; v.h = (_Float16)x; return v.u;
}
// packed fp16 convert (RTZ): low16 = f16(a), high16 = f16(b)
__device__ __forceinline__ u32 pkrtz(float a, float b) {
  u32 r;
  asm("v_cvt_pkrtz_f16_f32 %0, %1, %2" : "=v"(r) : "v"(a), "v"(b));
  return r;
}
// packed fp16: relu(p + q) on 2x16b at once
__device__ __forceinline__ u32 pk_addrelu_f16(u32 p, u32 q) {
  u32 r;
  asm("v_pk_add_f16 %0, %1, %2" : "=v"(r) : "v"(p), "v"(q));
  asm("v_pk_max_f16 %0, %1, 0"  : "=v"(r) : "v"(r));
  return r;
}
// global -> LDS direct copy, 16B/lane (wave-uniform LDS base + lane*16)
__device__ __forceinline__ void gload_lds16(const float* g, float* l) {
  __builtin_amdgcn_global_load_lds(
      (const __attribute__((address_space(1))) void*)g,
      (__attribute__((address_space(3))) void*)l, 16, 0, 0);
}
// 8 floats -> half8 (RNE)
__device__ __forceinline__ half8 cvt8(const float4 x, const float4 y) {
  half8 o;
  o[0]=(_Float16)x.x; o[1]=(_Float16)x.y; o[2]=(_Float16)x.z; o[3]=(_Float16)x.w;
  o[4]=(_Float16)y.x; o[5]=(_Float16)y.y; o[6]=(_Float16)y.z; o[7]=(_Float16)y.w;
  return o;
}

// ---------------------------------------------------------------------------
// Prep (1 block): W2h[r][k] = fp16(W2[r][k]) for r<8, zeros r=8..15
// ---------------------------------------------------------------------------
__global__ __launch_bounds__(256) void prep_w2(
    const float* __restrict__ W2, u16* __restrict__ W2h)
{
  const int t = threadIdx.x;        // 256 thr, 1 block
  const int r = t >> 4, c = t & 15; // row 0..15, 8-elem chunk 0..15
  short8 o;
  if (r < NTY) {
    const float4 x = *(const float4*)(W2 + (size_t)r * HF + 8 * c);
    const float4 y = *(const float4*)(W2 + (size_t)r * HF + 8 * c + 4);
    o[0]=(short)f2h(x.x); o[1]=(short)f2h(x.y); o[2]=(short)f2h(x.z); o[3]=(short)f2h(x.w);
    o[4]=(short)f2h(y.x); o[5]=(short)f2h(y.y); o[6]=(short)f2h(y.z); o[7]=(short)f2h(y.w);
  } else {
#pragma unroll
    for (int i = 0; i < 8; ++i) o[i] = 0;
  }
  *(short8*)(&W2h[(size_t)r * HF + 8 * c]) = o;
}

// ---------------------------------------------------------------------------
// Kernel A v8 (unchanged from r14 — inline W1 cvt, out of top-5):
//   PQ[n][j] = fp16( h[n]@W1a.T + b1 | h[n]@W1b.T )
//   All-fp16 MFMA, 32-node tiles, double-buffered gload_lds staging,
//   LDS-staged coalesced PQ stores.
// ---------------------------------------------------------------------------
__global__ __launch_bounds__(256) void node_pq_v8(
    const float* __restrict__ h, const float* __restrict__ W1,
    const float* __restrict__ b1, u16* __restrict__ PQ,
    int n_nodes, int n_tiles)
{
  __shared__ float Hs[2][32 * HF];     // 2 x 16 KB
  __shared__ uint2 Os2[32 * 64];       // 16 KB output tile (swizzled)
  const int t    = threadIdx.x;
  const int lane = t & 63;
  const int wq   = t >> 6;             // wave id = col quarter
  const int cl   = lane & 15;          // node-in-half (A-row / C col)
  const int kg   = lane >> 4;          // k-group (C rows 4kg..4kg+3)

  // ---- W fragments: inline f32 -> fp16 (RNE), resident in registers ----
  half8 af[4][4];
#pragma unroll
  for (int mi = 0; mi < 4; ++mi) {
    const int j = 64 * wq + 16 * mi + cl;
    const float* wr = W1 + (size_t)(j & 127) * 256 + ((j >> 7) << 7);
#pragma unroll
    for (int ks = 0; ks < 4; ++ks) {
      const float4 x = *(const float4*)(wr + 32 * ks + 8 * kg);
      const float4 y = *(const float4*)(wr + 32 * ks + 8 * kg + 4);
      af[mi][ks] = cvt8(x, y);
    }
  }
  float4 bias4[4];
#pragma unroll
  for (int mi = 0; mi < 4; ++mi) {
    if (wq < 2) bias4[mi] = *(const float4*)(b1 + 64 * wq + 16 * mi + 4 * kg);
    else        bias4[mi] = float4{0.0f, 0.0f, 0.0f, 0.0f};
  }

  // ---- stage 32 rows (16 KB): slot s -> row s>>5, chunk (s&31)^(row&7) ----
  auto stage = [&](int buf, int tile) {
#pragma unroll
    for (int i = 0; i < 4; ++i) {
      const int s  = i * 256 + t;      // 0..1023
      const int rr = s >> 5;           // row 0..31
      int node = tile * 32 + rr;
      if (node >= n_nodes) node = n_nodes - 1;
      const int c = (s & 31) ^ (rr & 7);
      gload_lds16(h + (size_t)node * HF + 4 * c,
                  &Hs[buf][(size_t)(i * 256 + (t & 192)) * 4]);
    }
  };

  const int stride = gridDim.x;
  int tile = blockIdx.x;
  int buf  = 0;
  if (tile < n_tiles) stage(0, tile);

  for (; tile < n_tiles; tile += stride) {
    __syncthreads();                   // A: buf staged; prev Os reads done
    const int nxt = tile + stride;
    if (nxt < n_tiles) stage(buf ^ 1, nxt);   // lands under this tile's compute

#pragma unroll
    for (int half = 0; half < 2; ++half) {
      const int row = half * 16 + cl;  // row&7 == cl&7 (16 = 0 mod 8)

      // ---- B operand: LDS row -> fp16 frags (k = 32ks + 8kg + i) ----
      half8 bhf[4];
#pragma unroll
      for (int ks = 0; ks < 4; ++ks) {
        const int c0 = (8 * ks + 2 * kg)     ^ (cl & 7);
        const int c1 = (8 * ks + 2 * kg + 1) ^ (cl & 7);
        const float4 x = *(const float4*)(&Hs[buf][row * HF + 4 * c0]);
        const float4 y = *(const float4*)(&Hs[buf][row * HF + 4 * c1]);
        union { u32 w[4]; half8 v; } B;
        B.w[0] = pkrtz(x.x, x.y);
        B.w[1] = pkrtz(x.z, x.w);
        B.w[2] = pkrtz(y.x, y.y);
        B.w[3] = pkrtz(y.z, y.w);
        bhf[ks] = B.v;
      }

      // ---- 4 j-tiles: 4 chained f16 MFMA, bias, pack -> swizzled Os ----
#pragma unroll
      for (int mi = 0; mi < 4; ++mi) {
        f32x4 acc = f32x4{0.0f, 0.0f, 0.0f, 0.0f};
#pragma unroll
        for (int ks = 0; ks < 4; ++ks)
          acc = __builtin_amdgcn_mfma_f32_16x16x32_f16(af[mi][ks], bhf[ks], acc, 0, 0, 0);
        acc[0] += bias4[mi].x; acc[1] += bias4[mi].y;
        acc[2] += bias4[mi].z; acc[3] += bias4[mi].w;
        uint2 o;
        o.x = pkrtz(acc[0], acc[1]);
        o.y = pkrtz(acc[2], acc[3]);
        Os2[row * 64 + ((16 * wq + 4 * mi + kg) ^ ((cl & 7) << 1))] = o;
      }
    }
    __syncthreads();                   // B: Os complete (and Hs[buf] reads done)

    // ---- coalesced PQ store: thread t writes 4 x 16B dense ----
    {
      const int tb = tile * 32;
#pragma unroll
      for (int i = 0; i < 4; ++i) {
        const int p   = i * 256 + t;   // 16B-unit id 0..1023
        const int row = p >> 5;
        const int node = tb + row;
        const uint4 v = *(const uint4*)&Os2[row * 64 + ((2 * (p & 31)) ^ ((row & 7) << 1))];
        if (node < n_nodes)
          *(uint4*)(&PQ[(size_t)node * 256 + (p & 31) * 8]) = v;
      }
    }
    buf ^= 1;
  }
}

// ---------------------------------------------------------------------------
// Kernel B v3 (r13-proven form: W2h preconverted, VGPR 44, occ ~40%).
//   At the L2-fill-rate ceiling: 110 MB / 128 B / 8 XCD = 1 line/cy/XCD.
// ---------------------------------------------------------------------------
__global__ __launch_bounds__(256, 4) void edge_mlp_dual(
    const u16* __restrict__ PQ, const int* __restrict__ src,
    const int* __restrict__ dst, const u16* __restrict__ W2h,
    const float* __restrict__ b2, float* __restrict__ out, int n_edges)
{
  const int t    = threadIdx.x;
  const int lane = t & 63;
  const int cl   = lane & 15;
  const int kg   = lane >> 4;
  const int base0 = (blockIdx.x * 4 + (t >> 6)) * 32;
  if (base0 >= n_edges) return;
  const int base1 = base0 + 16;

  int e0 = base0 + cl; if (e0 >= n_edges) e0 = n_edges - 1;
  int e1 = base1 + cl; if (e1 >= n_edges) e1 = n_edges - 1;

  const int s0 = src[e0], d0 = dst[e0];
  const int s1 = src[e1], d1 = dst[e1];

  const u16* pr0 = PQ + (size_t)s0 * 256 + 8 * kg;
  const u16* qr0 = PQ + (size_t)d0 * 256 + HF + 8 * kg;
  const u16* pr1 = PQ + (size_t)s1 * 256 + 8 * kg;
  const u16* qr1 = PQ + (size_t)d1 * 256 + HF + 8 * kg;
  uint4 P0[4], Q0[4], P1[4], Q1[4];
#pragma unroll
  for (int ks = 0; ks < 4; ++ks) P0[ks] = *(const uint4*)(pr0 + 32 * ks);
#pragma unroll
  for (int ks = 0; ks < 4; ++ks) Q0[ks] = *(const uint4*)(qr0 + 32 * ks);
#pragma unroll
  for (int ks = 0; ks < 4; ++ks) P1[ks] = *(const uint4*)(pr1 + 32 * ks);
#pragma unroll
  for (int ks = 0; ks < 4; ++ks) Q1[ks] = *(const uint4*)(qr1 + 32 * ks);

  half8 bf[4];
#pragma unroll
  for (int ks = 0; ks < 4; ++ks)
    bf[ks] = *(const half8*)(W2h + (size_t)cl * HF + 32 * ks + 8 * kg);
  const float bbias = (cl < NTY) ? b2[cl] : 0.0f;

  f32x4 acc0 = f32x4{0.0f, 0.0f, 0.0f, 0.0f};
  f32x4 acc1 = f32x4{0.0f, 0.0f, 0.0f, 0.0f};
#pragma unroll
  for (int ks = 0; ks < 4; ++ks) {
    union { u32 w[4]; half8 v; } a;
    a.w[0] = pk_addrelu_f16(P0[ks].x, Q0[ks].x);
    a.w[1] = pk_addrelu_f16(P0[ks].y, Q0[ks].y);
    a.w[2] = pk_addrelu_f16(P0[ks].z, Q0[ks].z);
    a.w[3] = pk_addrelu_f16(P0[ks].w, Q0[ks].w);
    acc0 = __builtin_amdgcn_mfma_f32_16x16x32_f16(a.v, bf[ks], acc0, 0, 0, 0);
  }
#pragma unroll
  for (int ks = 0; ks < 4; ++ks) {
    union { u32 w[4]; half8 v; } a;
    a.w[0] = pk_addrelu_f16(P1[ks].x, Q1[ks].x);
    a.w[1] = pk_addrelu_f16(P1[ks].y, Q1[ks].y);
    a.w[2] = pk_addrelu_f16(P1[ks].z, Q1[ks].z);
    a.w[3] = pk_addrelu_f16(P1[ks].w, Q1[ks].w);
    acc1 = __builtin_amdgcn_mfma_f32_16x16x32_f16(a.v, bf[ks], acc1, 0, 0, 0);
  }

  float v0[4], v1[4];
#pragma unroll
  for (int r = 0; r < 4; ++r) {
    {
      const float L = acc0[r] + bbias;
      float m = fmaxf(L, __shfl_xor(L, 1, 64));
      m = fmaxf(m, __shfl_xor(m, 2, 64));
      m = fmaxf(m, __shfl_xor(m, 4, 64));
      const float ex = __expf(L - m);
      float sm = ex + __shfl_xor(ex, 1, 64);
      sm += __shfl_xor(sm, 2, 64);
      sm += __shfl_xor(sm, 4, 64);
      v0[r] = ex / sm;
    }
    {
      const float L = acc1[r] + bbias;
      float m = fmaxf(L, __shfl_xor(L, 1, 64));
      m = fmaxf(m, __shfl_xor(m, 2, 64));
      m = fmaxf(m, __shfl_xor(m, 4, 64));
      const float ex = __expf(L - m);
      float sm = ex + __shfl_xor(ex, 1, 64);
      sm += __shfl_xor(sm, 2, 64);
      sm += __shfl_xor(sm, 4, 64);
      v1[r] = ex / sm;
    }
  }

  if (cl < NTY) {
#pragma unroll
    for (int r = 0; r < 4; ++r) {
      const int ee = base0 + 4 * kg + r;
      if (ee < n_edges) out[(size_t)ee * NTY + cl] = v0[r];
    }
#pragma unroll
    for (int r = 0; r < 4; ++r) {
      const int ee = base1 + 4 * kg + r;
      if (ee < n_edges) out[(size_t)ee * NTY + cl] = v1[r];
    }
  }
}

// ---------------------------------------------------------------------------
extern "C" void kernel_launch(void* const* d_in, const int* in_sizes, int n_in,
                              void* d_out, int out_size, void* d_ws, size_t ws_size,
                              hipStream_t stream) {
  const float* h   = (const float*)d_in[0];
  const int*   src = (const int*)d_in[1];
  const int*   dst = (const int*)d_in[2];
  const float* W1  = (const float*)d_in[3];
  const float* b1  = (const float*)d_in[4];
  const float* W2  = (const float*)d_in[5];
  const float* b2  = (const float*)d_in[6];
  float* out = (float*)d_out;

  const int n_nodes = in_sizes[0] / HF;   // 50000
  const int n_edges = in_sizes[1];        // 500000
  u16* PQ  = (u16*)d_ws;                  // [n_nodes][256] fp16 = 25.6 MB
  u16* W2h = PQ + (size_t)n_nodes * 256;  // [16][128] fp16 = 4 KB

  const int n_tiles = (n_nodes + 31) >> 5;            // 1563 (32-node tiles)
  const int nwav    = (n_edges + 31) >> 5;            // 15625 (32 edges/wave)
  const int nblk_e  = (nwav + 3) >> 2;                // 3907

  hipLaunchKernelGGL(prep_w2, dim3(1), dim3(256), 0, stream, W2, W2h);
  hipLaunchKernelGGL(node_pq_v8, dim3(768), dim3(256), 0, stream,
                     h, W1, b1, PQ, n_nodes, n_tiles);
  hipLaunchKernelGGL(edge_mlp_dual, dim3(nblk_e), dim3(256), 0, stream,
                     PQ, src, dst, W2h, b2, out, n_edges);
}

// Round 16
// 61.815 us; speedup vs baseline: 1.1398x; 1.1398x over previous
//
#include <hip/hip_runtime.h>
#include <cstdint>
#include <cstddef>

#define HF 128   // hidden feature dim
#define NTY 8    // edge types

typedef __attribute__((ext_vector_type(8))) short short8;     // 8 x 16b
typedef __attribute__((ext_vector_type(8))) _Float16 half8;   // 8 fp16
typedef __attribute__((ext_vector_type(4))) float f32x4;
typedef unsigned int u32;
typedef unsigned short u16;

__device__ __forceinline__ u16 f2h(float x) {      // RNE float->fp16 bits
  union { _Float16 h; u16 u; } v; v.h = (_Float16)x; return v.u;
}
// packed fp16 convert (RTZ): low16 = f16(a), high16 = f16(b)
__device__ __forceinline__ u32 pkrtz(float a, float b) {
  u32 r;
  asm("v_cvt_pkrtz_f16_f32 %0, %1, %2" : "=v"(r) : "v"(a), "v"(b));
  return r;
}
// packed fp16: relu(p + q) on 2x16b at once
__device__ __forceinline__ u32 pk_addrelu_f16(u32 p, u32 q) {
  u32 r;
  asm("v_pk_add_f16 %0, %1, %2" : "=v"(r) : "v"(p), "v"(q));
  asm("v_pk_max_f16 %0, %1, 0"  : "=v"(r) : "v"(r));
  return r;
}
// global -> LDS direct copy, 16B/lane (wave-uniform LDS base + lane*16)
__device__ __forceinline__ void gload_lds16(const float* g, float* l) {
  __builtin_amdgcn_global_load_lds(
      (const __attribute__((address_space(1))) void*)g,
      (__attribute__((address_space(3))) void*)l, 16, 0, 0);
}

// ---------------------------------------------------------------------------
// Prep (merged): blocks 0..15: W1 -> fp16 fragments in FRAGMENT-MAJOR layout
//   Wfrag[frag][lane][8], frag = wq*16 + mi*4 + ks, lane = 16*kg + cl,
//   value = fp16( W1[(j&127)][((j>>7)<<7) + 32ks + 8kg + i] ), j=64wq+16mi+cl
//   -> node kernel's per-wave fragment loads are fully coalesced (1KB dense).
// block 16: W2h[r][k] = fp16(W2[r][k]) for r<8, zeros r=8..15.
// ---------------------------------------------------------------------------
__global__ __launch_bounds__(256) void prep_weights(
    const float* __restrict__ W1, const float* __restrict__ W2,
    u16* __restrict__ Wfrag, u16* __restrict__ W2h)
{
  const int t = threadIdx.x;
  if (blockIdx.x < 16) {
    const int id = blockIdx.x * 256 + t;           // 0..4095
    const int j = id >> 4, c = id & 15;            // row j 0..255, chunk c 0..15
    const float* src = W1 + (size_t)(j & 127) * 256 + ((j >> 7) << 7) + 8 * c;
    const float4 x = *(const float4*)src;
    const float4 y = *(const float4*)(src + 4);
    short8 b;
    b[0]=(short)f2h(x.x); b[1]=(short)f2h(x.y); b[2]=(short)f2h(x.z); b[3]=(short)f2h(x.w);
    b[4]=(short)f2h(y.x); b[5]=(short)f2h(y.y); b[6]=(short)f2h(y.z); b[7]=(short)f2h(y.w);
    const int wq = j >> 6, mi = (j >> 4) & 3, cl = j & 15;
    const int ks = c >> 2, kg = c & 3;
    const int frag = wq * 16 + mi * 4 + ks;
    const int lane = 16 * kg + cl;
    *(short8*)(&Wfrag[(size_t)frag * 512 + lane * 8]) = b;
  } else {
    const int r = t >> 4, c = t & 15;              // row 0..15, chunk 0..15
    short8 o;
    if (r < NTY) {
      const float4 x = *(const float4*)(W2 + (size_t)r * HF + 8 * c);
      const float4 y = *(const float4*)(W2 + (size_t)r * HF + 8 * c + 4);
      o[0]=(short)f2h(x.x); o[1]=(short)f2h(x.y); o[2]=(short)f2h(x.z); o[3]=(short)f2h(x.w);
      o[4]=(short)f2h(y.x); o[5]=(short)f2h(y.y); o[6]=(short)f2h(y.z); o[7]=(short)f2h(y.w);
    } else {
#pragma unroll
      for (int i = 0; i < 8; ++i) o[i] = 0;
    }
    *(short8*)(&W2h[(size_t)r * HF + 8 * c]) = o;
  }
}

// ---------------------------------------------------------------------------
// Kernel A v9: PQ[n][j] = fp16( h[n]@W1a.T + b1 | h[n]@W1b.T )
//   = r13's v7 (all-fp16 MFMA, 32-node tiles, double-buffered gload_lds
//   staging, LDS-staged coalesced PQ stores) with W fragments loaded from
//   the fragment-major Wfrag layout: 16 fully-coalesced 1KB/wave loads.
// ---------------------------------------------------------------------------
__global__ __launch_bounds__(256) void node_pq_v9(
    const float* __restrict__ h, const u16* __restrict__ Wfrag,
    const float* __restrict__ b1, u16* __restrict__ PQ,
    int n_nodes, int n_tiles)
{
  __shared__ float Hs[2][32 * HF];     // 2 x 16 KB
  __shared__ uint2 Os2[32 * 64];       // 16 KB output tile (swizzled)
  const int t    = threadIdx.x;
  const int lane = t & 63;
  const int wq   = t >> 6;             // wave id = col quarter
  const int cl   = lane & 15;          // node-in-half (A-row / C col)
  const int kg   = lane >> 4;          // k-group (C rows 4kg..4kg+3)

  // ---- W fragments resident in registers (coalesced loads) ----
  half8 af[4][4];
#pragma unroll
  for (int mi = 0; mi < 4; ++mi)
#pragma unroll
    for (int ks = 0; ks < 4; ++ks)
      af[mi][ks] = *(const half8*)(Wfrag + (size_t)(wq * 16 + mi * 4 + ks) * 512 + lane * 8);

  float4 bias4[4];
#pragma unroll
  for (int mi = 0; mi < 4; ++mi) {
    if (wq < 2) bias4[mi] = *(const float4*)(b1 + 64 * wq + 16 * mi + 4 * kg);
    else        bias4[mi] = float4{0.0f, 0.0f, 0.0f, 0.0f};
  }

  // ---- stage 32 rows (16 KB): slot s -> row s>>5, chunk (s&31)^(row&7) ----
  auto stage = [&](int buf, int tile) {
#pragma unroll
    for (int i = 0; i < 4; ++i) {
      const int s  = i * 256 + t;      // 0..1023
      const int rr = s >> 5;           // row 0..31
      int node = tile * 32 + rr;
      if (node >= n_nodes) node = n_nodes - 1;
      const int c = (s & 31) ^ (rr & 7);
      gload_lds16(h + (size_t)node * HF + 4 * c,
                  &Hs[buf][(size_t)(i * 256 + (t & 192)) * 4]);
    }
  };

  const int stride = gridDim.x;
  int tile = blockIdx.x;
  int buf  = 0;
  if (tile < n_tiles) stage(0, tile);

  for (; tile < n_tiles; tile += stride) {
    __syncthreads();                   // A: buf staged; prev Os reads done
    const int nxt = tile + stride;
    if (nxt < n_tiles) stage(buf ^ 1, nxt);   // lands under this tile's compute

#pragma unroll
    for (int half = 0; half < 2; ++half) {
      const int row = half * 16 + cl;  // row&7 == cl&7 (16 = 0 mod 8)

      // ---- B operand: LDS row -> fp16 frags (k = 32ks + 8kg + i) ----
      half8 bhf[4];
#pragma unroll
      for (int ks = 0; ks < 4; ++ks) {
        const int c0 = (8 * ks + 2 * kg)     ^ (cl & 7);
        const int c1 = (8 * ks + 2 * kg + 1) ^ (cl & 7);
        const float4 x = *(const float4*)(&Hs[buf][row * HF + 4 * c0]);
        const float4 y = *(const float4*)(&Hs[buf][row * HF + 4 * c1]);
        union { u32 w[4]; half8 v; } B;
        B.w[0] = pkrtz(x.x, x.y);
        B.w[1] = pkrtz(x.z, x.w);
        B.w[2] = pkrtz(y.x, y.y);
        B.w[3] = pkrtz(y.z, y.w);
        bhf[ks] = B.v;
      }

      // ---- 4 j-tiles: 4 chained f16 MFMA, bias, pack -> swizzled Os ----
#pragma unroll
      for (int mi = 0; mi < 4; ++mi) {
        f32x4 acc = f32x4{0.0f, 0.0f, 0.0f, 0.0f};
#pragma unroll
        for (int ks = 0; ks < 4; ++ks)
          acc = __builtin_amdgcn_mfma_f32_16x16x32_f16(af[mi][ks], bhf[ks], acc, 0, 0, 0);
        acc[0] += bias4[mi].x; acc[1] += bias4[mi].y;
        acc[2] += bias4[mi].z; acc[3] += bias4[mi].w;
        uint2 o;
        o.x = pkrtz(acc[0], acc[1]);
        o.y = pkrtz(acc[2], acc[3]);
        Os2[row * 64 + ((16 * wq + 4 * mi + kg) ^ ((cl & 7) << 1))] = o;
      }
    }
    __syncthreads();                   // B: Os complete (and Hs[buf] reads done)

    // ---- coalesced PQ store: thread t writes 4 x 16B dense ----
    {
      const int tb = tile * 32;
#pragma unroll
      for (int i = 0; i < 4; ++i) {
        const int p   = i * 256 + t;   // 16B-unit id 0..1023
        const int row = p >> 5;
        const int node = tb + row;
        const uint4 v = *(const uint4*)&Os2[row * 64 + ((2 * (p & 31)) ^ ((row & 7) << 1))];
        if (node < n_nodes)
          *(uint4*)(&PQ[(size_t)node * 256 + (p & 31) * 8]) = v;
      }
    }
    buf ^= 1;
  }
}

// ---------------------------------------------------------------------------
// Kernel B v3 (r13-proven: W2h preconverted, VGPR 44, occ ~40% — at the
//   L2-fill-rate ceiling: 110 MB / 128 B / 8 XCD = 1 line/cy/XCD)
// ---------------------------------------------------------------------------
__global__ __launch_bounds__(256, 4) void edge_mlp_dual(
    const u16* __restrict__ PQ, const int* __restrict__ src,
    const int* __restrict__ dst, const u16* __restrict__ W2h,
    const float* __restrict__ b2, float* __restrict__ out, int n_edges)
{
  const int t    = threadIdx.x;
  const int lane = t & 63;
  const int cl   = lane & 15;
  const int kg   = lane >> 4;
  const int base0 = (blockIdx.x * 4 + (t >> 6)) * 32;
  if (base0 >= n_edges) return;
  const int base1 = base0 + 16;

  int e0 = base0 + cl; if (e0 >= n_edges) e0 = n_edges - 1;
  int e1 = base1 + cl; if (e1 >= n_edges) e1 = n_edges - 1;

  const int s0 = src[e0], d0 = dst[e0];
  const int s1 = src[e1], d1 = dst[e1];

  const u16* pr0 = PQ + (size_t)s0 * 256 + 8 * kg;
  const u16* qr0 = PQ + (size_t)d0 * 256 + HF + 8 * kg;
  const u16* pr1 = PQ + (size_t)s1 * 256 + 8 * kg;
  const u16* qr1 = PQ + (size_t)d1 * 256 + HF + 8 * kg;
  uint4 P0[4], Q0[4], P1[4], Q1[4];
#pragma unroll
  for (int ks = 0; ks < 4; ++ks) P0[ks] = *(const uint4*)(pr0 + 32 * ks);
#pragma unroll
  for (int ks = 0; ks < 4; ++ks) Q0[ks] = *(const uint4*)(qr0 + 32 * ks);
#pragma unroll
  for (int ks = 0; ks < 4; ++ks) P1[ks] = *(const uint4*)(pr1 + 32 * ks);
#pragma unroll
  for (int ks = 0; ks < 4; ++ks) Q1[ks] = *(const uint4*)(qr1 + 32 * ks);

  half8 bf[4];
#pragma unroll
  for (int ks = 0; ks < 4; ++ks)
    bf[ks] = *(const half8*)(W2h + (size_t)cl * HF + 32 * ks + 8 * kg);
  const float bbias = (cl < NTY) ? b2[cl] : 0.0f;

  f32x4 acc0 = f32x4{0.0f, 0.0f, 0.0f, 0.0f};
  f32x4 acc1 = f32x4{0.0f, 0.0f, 0.0f, 0.0f};
#pragma unroll
  for (int ks = 0; ks < 4; ++ks) {
    union { u32 w[4]; half8 v; } a;
    a.w[0] = pk_addrelu_f16(P0[ks].x, Q0[ks].x);
    a.w[1] = pk_addrelu_f16(P0[ks].y, Q0[ks].y);
    a.w[2] = pk_addrelu_f16(P0[ks].z, Q0[ks].z);
    a.w[3] = pk_addrelu_f16(P0[ks].w, Q0[ks].w);
    acc0 = __builtin_amdgcn_mfma_f32_16x16x32_f16(a.v, bf[ks], acc0, 0, 0, 0);
  }
#pragma unroll
  for (int ks = 0; ks < 4; ++ks) {
    union { u32 w[4]; half8 v; } a;
    a.w[0] = pk_addrelu_f16(P1[ks].x, Q1[ks].x);
    a.w[1] = pk_addrelu_f16(P1[ks].y, Q1[ks].y);
    a.w[2] = pk_addrelu_f16(P1[ks].z, Q1[ks].z);
    a.w[3] = pk_addrelu_f16(P1[ks].w, Q1[ks].w);
    acc1 = __builtin_amdgcn_mfma_f32_16x16x32_f16(a.v, bf[ks], acc1, 0, 0, 0);
  }

  float v0[4], v1[4];
#pragma unroll
  for (int r = 0; r < 4; ++r) {
    {
      const float L = acc0[r] + bbias;
      float m = fmaxf(L, __shfl_xor(L, 1, 64));
      m = fmaxf(m, __shfl_xor(m, 2, 64));
      m = fmaxf(m, __shfl_xor(m, 4, 64));
      const float ex = __expf(L - m);
      float sm = ex + __shfl_xor(ex, 1, 64);
      sm += __shfl_xor(sm, 2, 64);
      sm += __shfl_xor(sm, 4, 64);
      v0[r] = ex / sm;
    }
    {
      const float L = acc1[r] + bbias;
      float m = fmaxf(L, __shfl_xor(L, 1, 64));
      m = fmaxf(m, __shfl_xor(m, 2, 64));
      m = fmaxf(m, __shfl_xor(m, 4, 64));
      const float ex = __expf(L - m);
      float sm = ex + __shfl_xor(ex, 1, 64);
      sm += __shfl_xor(sm, 2, 64);
      sm += __shfl_xor(sm, 4, 64);
      v1[r] = ex / sm;
    }
  }

  if (cl < NTY) {
#pragma unroll
    for (int r = 0; r < 4; ++r) {
      const int ee = base0 + 4 * kg + r;
      if (ee < n_edges) out[(size_t)ee * NTY + cl] = v0[r];
    }
#pragma unroll
    for (int r = 0; r < 4; ++r) {
      const int ee = base1 + 4 * kg + r;
      if (ee < n_edges) out[(size_t)ee * NTY + cl] = v1[r];
    }
  }
}

// ---------------------------------------------------------------------------
extern "C" void kernel_launch(void* const* d_in, const int* in_sizes, int n_in,
                              void* d_out, int out_size, void* d_ws, size_t ws_size,
                              hipStream_t stream) {
  const float* h   = (const float*)d_in[0];
  const int*   src = (const int*)d_in[1];
  const int*   dst = (const int*)d_in[2];
  const float* W1  = (const float*)d_in[3];
  const float* b1  = (const float*)d_in[4];
  const float* W2  = (const float*)d_in[5];
  const float* b2  = (const float*)d_in[6];
  float* out = (float*)d_out;

  const int n_nodes = in_sizes[0] / HF;     // 50000
  const int n_edges = in_sizes[1];          // 500000
  u16* PQ    = (u16*)d_ws;                  // [n_nodes][256] fp16 = 25.6 MB
  u16* Wfrag = PQ + (size_t)n_nodes * 256;  // [64][64][8] fp16 = 64 KB
  u16* W2h   = Wfrag + 64 * 512;            // [16][128] fp16 = 4 KB

  const int n_tiles = (n_nodes + 31) >> 5;            // 1563 (32-node tiles)
  const int nwav    = (n_edges + 31) >> 5;            // 15625 (32 edges/wave)
  const int nblk_e  = (nwav + 3) >> 2;                // 3907

  hipLaunchKernelGGL(prep_weights, dim3(17), dim3(256), 0, stream,
                     W1, W2, Wfrag, W2h);
  hipLaunchKernelGGL(node_pq_v9, dim3(768), dim3(256), 0, stream,
                     h, Wfrag, b1, PQ, n_nodes, n_tiles);
  hipLaunchKernelGGL(edge_mlp_dual, dim3(nblk_e), dim3(256), 0, stream,
                     PQ, src, dst, W2h, b2, out, n_edges);
}